// Round 11
// baseline (158.511 us; speedup 1.0000x reference)
//
#include <hip/hip_runtime.h>
#include <hip/hip_bf16.h>

// Problem constants
#define BB 512   // batch
#define SS 96    // seq len
#define NN 64    // nodes
#define HH 512   // hidden
#define EE 512   // edges per graph

typedef __attribute__((ext_vector_type(8))) short short8;   // 8 bf16 (4 VGPRs)
typedef __attribute__((ext_vector_type(4))) float f32x4;    // MFMA acc
typedef unsigned short u16;

__device__ __forceinline__ u16 f2bf(float f) {
    union { float f; unsigned u; } v; v.f = f;
    return (u16)((v.u + 0x7FFFu + ((v.u >> 16) & 1u)) >> 16);   // RNE
}
__device__ __forceinline__ short8 ld8bf(const u16* p) { return *(const short8*)p; }
__device__ __forceinline__ short8 cvt8(const float* p) {       // 8 fp32 -> bf16 frag
    float4 a = *(const float4*)p, b = *(const float4*)(p + 4);
    short8 r;
    r[0] = (short)f2bf(a.x); r[1] = (short)f2bf(a.y);
    r[2] = (short)f2bf(a.z); r[3] = (short)f2bf(a.w);
    r[4] = (short)f2bf(b.x); r[5] = (short)f2bf(b.y);
    r[6] = (short)f2bf(b.z); r[7] = (short)f2bf(b.w);
    return r;
}
__device__ __forceinline__ ushort4 packbf(f32x4 a) {
    ushort4 u; u.x = f2bf(a[0]); u.y = f2bf(a[1]); u.z = f2bf(a[2]); u.w = f2bf(a[3]);
    return u;
}

// Staged-chunk geometry: per hc (64 hidden), one contiguous 27136-B pair:
//   [0,13312):  W1 chunk  [64 rows h][104 u16] (cols 96..103 pad)
//   [13312,27136): W2 chunk [96 rows s][72 u16] (cols 64..71 pad)
#define CHUNK_B  27136
#define CHUNK_U  13568
#define W2OFF_U  6656

// ---------------------------------------------------------------------------
// k_prep (merged, grid 512): weight reshape (grid-stride, single pass) +
// per-graph normalized adjacency -> AsG bf16 [64][64] (block b = graph b).
// Merging removes one kernel launch + strips phase0 (atomics + 5 barriers)
// out of k_all so k_all starts with pure overlappable global loads.
// ---------------------------------------------------------------------------
__global__ __launch_bounds__(256) void k_prep(const float* __restrict__ W1,
                                              const float* __restrict__ W2,
                                              const float* __restrict__ cw,
                                              const int* __restrict__ ei,
                                              u16* __restrict__ Wcb,
                                              u16* __restrict__ W12s,
                                              u16* __restrict__ AsG) {
    const int b = blockIdx.x, t = threadIdx.x;
    const int i0 = b * 256 + t, stp = 512 * 256;
    // ---- weight prep (grid-stride across all 512 blocks; <=1 iter each) ----
    for (int i = i0; i < HH * 192; i += stp) {
        int h = i / 192, q = i % 192, n = q / 3, kw = q % 3;
        Wcb[h * 192 + kw * 64 + n] = f2bf(cw[i]);
    }
    for (int i = i0; i < 8 * CHUNK_U; i += stp) {
        int hc = i / CHUNK_U, q = i % CHUNK_U;
        float v = 0.f;
        if (q < W2OFF_U) {                         // W1 part [64][104]
            int r = q / 104, c = q % 104;
            if (c < 96) v = W1[(hc * 64 + r) * 96 + c];
        } else {                                   // W2 part [96][72]
            int q2 = q - W2OFF_U, s = q2 / 72, c = q2 % 72;
            if (c < 64) v = W2[s * 512 + hc * 64 + c];
        }
        W12s[i] = f2bf(v);
    }
    // ---- adjacency for graph b ----
    __shared__ float Asm[4096];
    __shared__ int   deg[64];
    __shared__ float dinv[64];
    for (int i = t; i < 4096; i += 256) Asm[i] = 0.f;
    if (t < 64) deg[t] = 1;                          // self loop
    __syncthreads();
    const int* eb = ei + (size_t)b * 2 * EE;
    const int es0 = eb[t],       ed0 = eb[EE + t];
    const int es1 = eb[256 + t], ed1 = eb[EE + 256 + t];
    atomicAdd(&deg[ed0], 1);
    atomicAdd(&deg[ed1], 1);
    __syncthreads();
    if (t < 64) dinv[t] = rsqrtf((float)deg[t]);
    __syncthreads();
    atomicAdd(&Asm[ed0 * 64 + es0], dinv[es0] * dinv[ed0]);
    atomicAdd(&Asm[ed1 * 64 + es1], dinv[es1] * dinv[ed1]);
    if (t < 64) atomicAdd(&Asm[t * 64 + t], dinv[t] * dinv[t]);
    __syncthreads();
    u16* ab = AsG + (size_t)b * 4096;
    for (int i = t; i < 1024; i += 256) {
        int n = i >> 4, m4 = (i & 15) * 4;
        f32x4 v = *(const f32x4*)(Asm + n * 64 + m4);
        *(ushort4*)(ab + n * 64 + m4) = packbf(v);
    }
}

// ---------------------------------------------------------------------------
// k_all: FUSED, 512 threads (8 waves) per graph.  ROUND-11 = round-10 with
// the nontemporal-store type fixed (f32x4 ext-vector, not HIP float4).
//  - adjacency precomputed (af frags straight from AsG global; L2/L3-hot)
//  - hidden loop: wave-PRIVATE H1 tile (producer==consumer transpose, the
//    r0-r4 pattern) -> MFMA1 covers all 4 hs per wave (redundant W1 reads
//    now hit staged LDS = cheap); ONE barrier per hc (chunk handoff only)
//  - conv stores nontemporal (100MB stream must not evict 413KB weights)
// Barriers: ~11 total (was ~21).  Blocks stay lockstep (r7 lesson).
// Wave split: wg=w&3 node-group, p=w>>2 j-half (MFMA0/MFMA2/MFMA3/Ts).
// LDS map (79744 B):
//   buf0@0(27136) buf1@27136(27136) Gs@54272[64][104](13312)
//   b1L@76800(2048) b2L@78848(384)
//   overlays: H1priv@54272 8x[16][72]=18432 (over Gs after gb extraction)
//             Ts[96][72]@0, Hp[98][72]@13824 (over bufs post-loop)
//   2 blocks/CU (159488 <= 163840); launch_bounds(512,4) caps VGPR 128.
// ---------------------------------------------------------------------------
__global__ __launch_bounds__(512, 4) void k_all(const float* __restrict__ x,
                                                const u16* __restrict__ AsG,
                                                const float* __restrict__ b1,
                                                const float* __restrict__ b2,
                                                const u16* __restrict__ Wcb,
                                                const u16* __restrict__ W12s,
                                                float* __restrict__ out) {
    const int b = blockIdx.x, t = threadIdx.x;
    const int w = t >> 6, lane = t & 63, quad = lane >> 4, l16 = lane & 15;
    const int wg = w & 3, p = w >> 2;

    __shared__ __align__(16) char smem[79744];
    u16*   Gs     = (u16*)(smem + 54272);
    u16*   H1priv = (u16*)(smem + 54272);   // overlay after gb extraction
    float* b1L    = (float*)(smem + 76800);
    float* b2L    = (float*)(smem + 78848);
    u16*   Ts     = (u16*)smem;             // overlay (post-loop)
    u16*   Hp     = (u16*)(smem + 13824);   // overlay (post-loop)

    // ---- staging offsets (flat 16B units over one 27136-B chunk-pair) ----
    int so[4];
    #pragma unroll
    for (int rr = 0; rr < 4; ++rr) so[rr] = rr * 8192 + w * 1024 + lane * 16;

    // ---- front loads, all independent: hc0 chunk, af frags, biases ----
    const char* wsrc = (const char*)W12s;
    short8 st[4];
    #pragma unroll
    for (int rr = 0; rr < 4; ++rr)
        if (so[rr] < CHUNK_B) st[rr] = ld8bf((const u16*)(wsrc + so[rr]));
    const u16* asb = AsG + (size_t)b * 4096;
    short8 af[2];
    #pragma unroll
    for (int kc = 0; kc < 2; ++kc)
        af[kc] = ld8bf(asb + (wg * 16 + l16) * 64 + kc * 32 + quad * 8);
    b1L[t] = b1[t];
    if (t < 96) b2L[t] = b2[t];

    // ---- MFMA0: Gs[node][s] = X @ A^T  (wave: nodes=wg, j-half=p) ----
    {
        const float* xb = x + (size_t)b * SS * NN;
        #pragma unroll
        for (int jj = 0; jj < 3; ++jj) {
            const int j = p * 3 + jj;
            f32x4 acc = (f32x4){0.f, 0.f, 0.f, 0.f};
            #pragma unroll
            for (int kc = 0; kc < 2; ++kc) {
                short8 a = cvt8(xb + (j * 16 + l16) * 64 + kc * 32 + quad * 8);
                acc = __builtin_amdgcn_mfma_f32_16x16x32_bf16(a, af[kc], acc, 0, 0, 0);
            }
            // col=l16 -> node=wg*16+l16 ; row=quad*4+r -> s=j*16+quad*4+r
            *(ushort4*)(Gs + (wg * 16 + l16) * 104 + j * 16 + quad * 4) = packbf(acc);
        }
    }
    // ds_write staged hc0 -> buf0 (st loads drained during MFMA0)
    #pragma unroll
    for (int rr = 0; rr < 4; ++rr)
        if (so[rr] < CHUNK_B) *(short8*)(smem + so[rr]) = st[rr];
    __syncthreads();                           // B1: Gs + buf0 + biases visible

    short8 gb[3];
    #pragma unroll
    for (int kc = 0; kc < 3; ++kc)
        gb[kc] = ld8bf(Gs + (wg * 16 + l16) * 104 + kc * 32 + quad * 8);
    __syncthreads();                           // B2: all gb read; Gs -> H1priv

    // ---- hidden loop: 1 barrier/hc.  Wave-private H1 (16 nodes x 64 h). ----
    f32x4 accT[3];
    #pragma unroll
    for (int jj = 0; jj < 3; ++jj) accT[jj] = (f32x4){0.f, 0.f, 0.f, 0.f};
    u16* H1w = H1priv + w * 1152;              // [16][72] u16

    for (int hc = 0; hc < 8; ++hc) {
        const u16* wbuf = (const u16*)(smem + (hc & 1) * CHUNK_B);
        // issue next chunk's loads (land during MFMA1/MFMA2)
        if (hc < 7) {
            const char* src = wsrc + (size_t)(hc + 1) * CHUNK_B;
            #pragma unroll
            for (int rr = 0; rr < 4; ++rr)
                if (so[rr] < CHUNK_B) st[rr] = ld8bf((const u16*)(src + so[rr]));
        }
        // MFMA1: all 4 hs for this wave's 16 nodes -> private transpose tile
        #pragma unroll
        for (int hs = 0; hs < 4; ++hs) {
            f32x4 a1 = (f32x4){0.f, 0.f, 0.f, 0.f};
            #pragma unroll
            for (int kc = 0; kc < 3; ++kc) {
                short8 wa = ld8bf(wbuf + (hs * 16 + l16) * 104 + kc * 32 + quad * 8);
                a1 = __builtin_amdgcn_mfma_f32_16x16x32_bf16(wa, gb[kc], a1, 0, 0, 0);
            }
            float4 bias = *(const float4*)(b1L + hc * 64 + hs * 16 + quad * 4);
            f32x4 r;
            r[0] = fmaxf(a1[0] + bias.x, 0.f); r[1] = fmaxf(a1[1] + bias.y, 0.f);
            r[2] = fmaxf(a1[2] + bias.z, 0.f); r[3] = fmaxf(a1[3] + bias.w, 0.f);
            // col=l16 -> local node ; row h=hs*16+quad*4+r
            *(ushort4*)(H1w + l16 * 72 + hs * 16 + quad * 4) = packbf(r);
        }
        // ha from own tile (same-wave LDS, program-ordered; no barrier)
        short8 ha[2];
        #pragma unroll
        for (int kc = 0; kc < 2; ++kc)
            ha[kc] = ld8bf(H1w + l16 * 72 + kc * 32 + quad * 8);
        // MFMA2: accT[node][s] += H1 @ W2c^T  (j = p*3+jj)
        #pragma unroll
        for (int jj = 0; jj < 3; ++jj) {
            const int j = p * 3 + jj;
            #pragma unroll
            for (int kc = 0; kc < 2; ++kc) {
                short8 wb = ld8bf(wbuf + W2OFF_U + (j * 16 + l16) * 72 + kc * 32 + quad * 8);
                accT[jj] = __builtin_amdgcn_mfma_f32_16x16x32_bf16(ha[kc], wb, accT[jj], 0, 0, 0);
            }
        }
        // relay staged regs into the idle buffer (its readers ended last iter)
        if (hc < 7) {
            char* dst = smem + ((hc + 1) & 1) * CHUNK_B;
            #pragma unroll
            for (int rr = 0; rr < 4; ++rr)
                if (so[rr] < CHUNK_B) *(short8*)(dst + so[rr]) = st[rr];
        }
        __syncthreads();                       // chunk handoff (1 per hc)
    }

    // ---- Ts[s][m] <- accT (overlay buf0; disjoint from iter-7 reads) ----
    #pragma unroll
    for (int jj = 0; jj < 3; ++jj) {
        const int j = p * 3 + jj;   // col=l16 -> s=j*16+l16 ; rows node=wg*16+quad*4+r
        *(ushort4*)(Ts + (j * 16 + l16) * 72 + wg * 16 + quad * 4) = packbf(accT[jj]);
    }
    __syncthreads();                           // B3

    // ---- MFMA3: Hp[s+1][n] = A @ T + b2 (af in regs; pad folded in) ----
    #pragma unroll
    for (int jj = 0; jj < 3; ++jj) {
        const int j = p * 3 + jj;
        f32x4 a3 = (f32x4){0.f, 0.f, 0.f, 0.f};
        #pragma unroll
        for (int kc = 0; kc < 2; ++kc) {
            short8 tb = ld8bf(Ts + (j * 16 + l16) * 72 + kc * 32 + quad * 8);
            a3 = __builtin_amdgcn_mfma_f32_16x16x32_bf16(af[kc], tb, a3, 0, 0, 0);
        }
        float bs = b2L[j * 16 + l16];
        f32x4 r = {a3[0] + bs, a3[1] + bs, a3[2] + bs, a3[3] + bs};
        ushort4 pr = packbf(r);
        // col=l16 -> s=j*16+l16 ; rows n=wg*16+quad*4+rr
        *(ushort4*)(Hp + (j * 16 + l16 + 1) * 72 + wg * 16 + quad * 4) = pr;
        if (j == 5 && l16 == 15) *(ushort4*)(Hp + 0 * 72  + wg * 16 + quad * 4) = pr;
        if (j == 0 && l16 == 0)  *(ushort4*)(Hp + 97 * 72 + wg * 16 + quad * 4) = pr;
    }
    __syncthreads();                           // B4

    // ---- conv: 8-wave split; nontemporal stores (protect L2 weight set) ----
    const int wc = w & 3, wt = w >> 2;
    float* ob = out + (size_t)b * SS * HH;
    #pragma unroll
    for (int htt = 0; htt < 4; ++htt) {
        const int ht = wt * 4 + htt;
        short8 wa[6];
        #pragma unroll
        for (int kc = 0; kc < 6; ++kc)
            wa[kc] = ld8bf(Wcb + (size_t)(ht * 64 + wc * 16 + l16) * 192 + kc * 32 + quad * 8);
        #pragma unroll
        for (int j = 0; j < 6; ++j) {
            f32x4 acc = (f32x4){0.f, 0.f, 0.f, 0.f};
            #pragma unroll
            for (int kc = 0; kc < 6; ++kc) {
                int kw = kc >> 1, nb = (kc & 1) * 32;
                short8 hb = ld8bf(Hp + (j * 16 + l16 + kw) * 72 + nb + quad * 8);
                acc = __builtin_amdgcn_mfma_f32_16x16x32_bf16(wa[kc], hb, acc, 0, 0, 0);
            }
            // col=l16 -> s=j*16+l16 ; rows h=ht*64+wc*16+quad*4+rr
            // nontemporal store via native ext-vector type (f32x4), not HIP float4
            f32x4* dst = (f32x4*)(ob + (size_t)(j * 16 + l16) * HH + ht * 64 + wc * 16 + quad * 4);
            __builtin_nontemporal_store(acc, dst);
        }
    }
}

// ---------------------------------------------------------------------------
extern "C" void kernel_launch(void* const* d_in, const int* in_sizes, int n_in,
                              void* d_out, int out_size, void* d_ws, size_t ws_size,
                              hipStream_t stream) {
    const float* x  = (const float*)d_in[0];
    const int*   ei = (const int*)d_in[1];
    const float* W1 = (const float*)d_in[2];
    const float* b1 = (const float*)d_in[3];
    const float* W2 = (const float*)d_in[4];
    const float* b2 = (const float*)d_in[5];
    const float* cw = (const float*)d_in[6];
    float* out = (float*)d_out;

    char* wsp = (char*)d_ws;
    u16* Wcb  = (u16*)wsp;                   // 196,608 B
    u16* W12s = (u16*)(wsp + 196608);        // 217,088 B
    u16* AsG  = (u16*)(wsp + 413696);        // 4,194,304 B

    k_prep<<<BB, 256, 0, stream>>>(W1, W2, cw, ei, Wcb, W12s, AsG);
    k_all <<<BB, 512, 0, stream>>>(x, AsG, b1, b2, Wcb, W12s, out);
}